// Round 1
// baseline (4133.437 us; speedup 1.0000x reference)
//
#include <hip/hip_runtime.h>
#include <hip/hip_bf16.h>
#include <math.h>

#define Nn 20000
#define Ee 320000
#define Dd 512
#define Hh 4
#define Cc 256
#define Ll 4
#define Bb 16
#define HC 1024               // H*C
#define ETOT (Ee + Nn)        // edges + self loops = 340000
#define NEG_SLOPE 0.2f
#define LN_EPS 1e-5f

// ---------------- CSR build ----------------

__device__ __forceinline__ void decode_edge(const int* ei, int e, int& s, int& d) {
    if (e < Ee) { s = ei[e]; d = ei[Ee + e]; }
    else        { s = e - Ee; d = e - Ee; }   // self loop
}

__global__ void count_deg_kernel(const int* __restrict__ ei, int* __restrict__ deg) {
    int e = blockIdx.x * blockDim.x + threadIdx.x;
    if (e >= ETOT) return;
    int s, d; decode_edge(ei, e, s, d);
    atomicAdd(&deg[d], 1);
}

// single-block exclusive scan over deg[0..N-1] -> row_ptr[0..N]
__global__ void scan_kernel(const int* __restrict__ deg, int* __restrict__ row_ptr) {
    __shared__ int sdata[1024];
    __shared__ int carry;
    int tid = threadIdx.x;
    if (tid == 0) { carry = 0; row_ptr[0] = 0; }
    __syncthreads();
    for (int base = 0; base < Nn; base += 1024) {
        int i = base + tid;
        int v = (i < Nn) ? deg[i] : 0;
        sdata[tid] = v;
        __syncthreads();
        for (int off = 1; off < 1024; off <<= 1) {
            int t = (tid >= off) ? sdata[tid - off] : 0;
            __syncthreads();
            sdata[tid] += t;
            __syncthreads();
        }
        if (i < Nn) row_ptr[i + 1] = carry + sdata[tid];
        __syncthreads();
        if (tid == 1023) carry += sdata[1023];
        __syncthreads();
    }
}

__global__ void cursor_init_kernel(const int* __restrict__ row_ptr, int* __restrict__ cursor) {
    int i = blockIdx.x * blockDim.x + threadIdx.x;
    if (i < Nn) cursor[i] = row_ptr[i];
}

__global__ void scatter_kernel(const int* __restrict__ ei, int* __restrict__ cursor,
                               int* __restrict__ csr_src) {
    int e = blockIdx.x * blockDim.x + threadIdx.x;
    if (e >= ETOT) return;
    int s, d; decode_edge(ei, e, s, d);
    int pos = atomicAdd(&cursor[d], 1);
    csr_src[pos] = s;
}

// ---------------- GEMM: C[M,1024] = A[M,K] @ W[K,1024] ----------------
// BM=BN=64, BK=16, 256 threads, 4x4 microtile per thread.

__global__ __launch_bounds__(256) void gemm_kernel(const float* __restrict__ A,
                                                   const float* __restrict__ W,
                                                   float* __restrict__ Cmat,
                                                   int M, int K) {
    __shared__ float As[16][68];   // padded: 68%4==0 keeps float4 alignment
    __shared__ float Bs[16][68];
    const int Ncol = HC;
    int tid = threadIdx.x;
    int tx = tid & 15, ty = tid >> 4;
    int rowBase = blockIdx.y * 64;
    int colBase = blockIdx.x * 64;
    float acc[4][4] = {};
    for (int k0 = 0; k0 < K; k0 += 16) {
        #pragma unroll
        for (int i = tid; i < 64 * 16; i += 256) {
            int m = i >> 4, k = i & 15;
            int r = rowBase + m;
            As[k][m] = (r < M) ? A[(size_t)r * K + k0 + k] : 0.f;
        }
        #pragma unroll
        for (int i = tid; i < 16 * 64; i += 256) {
            int k = i >> 6, nn = i & 63;
            Bs[k][nn] = W[(size_t)(k0 + k) * Ncol + colBase + nn];
        }
        __syncthreads();
        #pragma unroll
        for (int k = 0; k < 16; ++k) {
            float4 a4 = *(const float4*)&As[k][ty * 4];
            float4 b4 = *(const float4*)&Bs[k][tx * 4];
            float a[4] = {a4.x, a4.y, a4.z, a4.w};
            float b[4] = {b4.x, b4.y, b4.z, b4.w};
            #pragma unroll
            for (int i = 0; i < 4; ++i)
                #pragma unroll
                for (int j = 0; j < 4; ++j)
                    acc[i][j] += a[i] * b[j];
        }
        __syncthreads();
    }
    #pragma unroll
    for (int i = 0; i < 4; ++i) {
        int r = rowBase + ty * 4 + i;
        if (r < M) {
            #pragma unroll
            for (int j = 0; j < 4; ++j)
                Cmat[(size_t)r * Ncol + colBase + tx * 4 + j] = acc[i][j];
        }
    }
}

// ---------------- attention logits per node/head ----------------

__global__ void alpha_kernel(const float* __restrict__ hfeat,
                             const float* __restrict__ att_src_l,
                             const float* __restrict__ att_dst_l,
                             float* __restrict__ asrc, float* __restrict__ adst) {
    int n = blockIdx.x;
    int hh = threadIdx.x >> 6;
    int lane = threadIdx.x & 63;
    float s1 = 0.f, s2 = 0.f;
    #pragma unroll
    for (int c = lane; c < Cc; c += 64) {
        float v = hfeat[(size_t)n * HC + hh * Cc + c];
        s1 += v * att_src_l[hh * Cc + c];
        s2 += v * att_dst_l[hh * Cc + c];
    }
    #pragma unroll
    for (int off = 32; off > 0; off >>= 1) {
        s1 += __shfl_down(s1, off);
        s2 += __shfl_down(s2, off);
    }
    if (lane == 0) {
        asrc[n * Hh + hh] = s1;
        adst[n * Hh + hh] = s2;
    }
}

// ---------------- softmax-weighted aggregation ----------------
// one block per (node, head); 256 threads = 256 channels

__global__ __launch_bounds__(256) void agg_kernel(const float* __restrict__ hfeat,
                                                  const float* __restrict__ asrc,
                                                  const float* __restrict__ adst,
                                                  const int* __restrict__ row_ptr,
                                                  const int* __restrict__ csr_src,
                                                  const float* __restrict__ bias_l,
                                                  float* __restrict__ out) {
    int n = blockIdx.x, hh = blockIdx.y;
    int tid = threadIdx.x;
    int start = row_ptr[n], end = row_ptr[n + 1];
    float adst_n = adst[n * Hh + hh];
    __shared__ float red[256];

    // phase 1: segment max
    float mx = -INFINITY;
    for (int e = start + tid; e < end; e += 256) {
        int s = csr_src[e];
        float z = asrc[s * Hh + hh] + adst_n;
        z = (z > 0.f) ? z : NEG_SLOPE * z;
        mx = fmaxf(mx, z);
    }
    red[tid] = mx;
    __syncthreads();
    for (int off = 128; off > 0; off >>= 1) {
        if (tid < off) red[tid] = fmaxf(red[tid], red[tid + off]);
        __syncthreads();
    }
    float m = red[0];
    __syncthreads();

    // phase 2: denom
    float sm = 0.f;
    for (int e = start + tid; e < end; e += 256) {
        int s = csr_src[e];
        float z = asrc[s * Hh + hh] + adst_n;
        z = (z > 0.f) ? z : NEG_SLOPE * z;
        sm += expf(z - m);
    }
    red[tid] = sm;
    __syncthreads();
    for (int off = 128; off > 0; off >>= 1) {
        if (tid < off) red[tid] += red[tid + off];
        __syncthreads();
    }
    float denom = red[0] + 1e-16f;
    __syncthreads();

    // phase 3: weighted accumulate, channel c = tid
    float acc = 0.f;
    for (int e = start; e < end; ++e) {
        int s = csr_src[e];
        float z = asrc[s * Hh + hh] + adst_n;
        z = (z > 0.f) ? z : NEG_SLOPE * z;
        float w = expf(z - m) / denom;
        acc += w * hfeat[(size_t)s * HC + hh * Cc + tid];
    }
    float v = acc + bias_l[hh * Cc + tid];
    out[(size_t)n * HC + hh * Cc + tid] = fmaxf(v, 0.f);   // relu
}

// ---------------- global mean pool ----------------

__global__ void pool_kernel(const float* __restrict__ hnode, const int* __restrict__ batch,
                            float* __restrict__ pooled, float* __restrict__ counts) {
    int n = blockIdx.x;
    int b = batch[n];
    for (int c = threadIdx.x; c < HC; c += 256)
        atomicAdd(&pooled[b * HC + c], hnode[(size_t)n * HC + c]);
    if (threadIdx.x == 0) atomicAdd(&counts[b], 1.0f);
}

// ---------------- projection + layernorm ----------------

__global__ __launch_bounds__(512) void final_kernel(const float* __restrict__ pooled,
                                                    const float* __restrict__ counts,
                                                    const float* __restrict__ projW,
                                                    const float* __restrict__ projb,
                                                    const float* __restrict__ gamma,
                                                    const float* __restrict__ beta,
                                                    float* __restrict__ out) {
    int b = blockIdx.x;
    int d = threadIdx.x;           // 512 threads
    __shared__ float p[HC];
    __shared__ float red[512];
    float inv = 1.0f / fmaxf(counts[b], 1.0f);
    for (int k = d; k < HC; k += 512) p[k] = pooled[b * HC + k] * inv;
    __syncthreads();
    float o = projb[d];
    for (int k = 0; k < HC; ++k) o += p[k] * projW[(size_t)k * Dd + d];
    red[d] = o;
    __syncthreads();
    for (int off = 256; off > 0; off >>= 1) {
        if (d < off) red[d] += red[d + off];
        __syncthreads();
    }
    float mu = red[0] / (float)Dd;
    __syncthreads();
    float df = o - mu;
    red[d] = df * df;
    __syncthreads();
    for (int off = 256; off > 0; off >>= 1) {
        if (d < off) red[d] += red[d + off];
        __syncthreads();
    }
    float var = red[0] / (float)Dd;
    out[b * Dd + d] = df / sqrtf(var + LN_EPS) * gamma[d] + beta[d];
}

// ---------------- launch ----------------

extern "C" void kernel_launch(void* const* d_in, const int* in_sizes, int n_in,
                              void* d_out, int out_size, void* d_ws, size_t ws_size,
                              hipStream_t stream) {
    const float* x         = (const float*)d_in[0];
    const int*   ei        = (const int*)d_in[1];
    const int*   batch     = (const int*)d_in[2];
    const float* W0        = (const float*)d_in[3];
    const float* W_rest    = (const float*)d_in[4];
    const float* att_src   = (const float*)d_in[5];
    const float* att_dst   = (const float*)d_in[6];
    const float* conv_bias = (const float*)d_in[7];
    const float* proj_W    = (const float*)d_in[8];
    const float* proj_b    = (const float*)d_in[9];
    const float* ln_gamma  = (const float*)d_in[10];
    const float* ln_beta   = (const float*)d_in[11];
    float* out = (float*)d_out;

    // workspace layout (bytes, 256-aligned)
    char* ws = (char*)d_ws;
    size_t off = 0;
    auto alloc = [&](size_t bytes) {
        void* p = ws + off;
        off = (off + bytes + 255) & ~(size_t)255;
        return p;
    };
    float* h1      = (float*)alloc((size_t)Nn * HC * 4);   // pre-agg features
    float* h2      = (float*)alloc((size_t)Nn * HC * 4);   // layer output
    float* asrc    = (float*)alloc((size_t)Nn * Hh * 4);
    float* adst    = (float*)alloc((size_t)Nn * Hh * 4);
    int*   deg     = (int*)alloc((size_t)Nn * 4);
    int*   row_ptr = (int*)alloc((size_t)(Nn + 1) * 4);
    int*   cursor  = (int*)alloc((size_t)Nn * 4);
    int*   csr_src = (int*)alloc((size_t)ETOT * 4);
    float* pooled  = (float*)alloc((size_t)Bb * HC * 4);
    float* counts  = (float*)alloc((size_t)Bb * 4);
    (void)ws_size; (void)in_sizes; (void)n_in; (void)out_size;

    // ---- build CSR by destination ----
    hipMemsetAsync(deg, 0, (size_t)Nn * 4, stream);
    count_deg_kernel<<<(ETOT + 255) / 256, 256, 0, stream>>>(ei, deg);
    scan_kernel<<<1, 1024, 0, stream>>>(deg, row_ptr);
    cursor_init_kernel<<<(Nn + 255) / 256, 256, 0, stream>>>(row_ptr, cursor);
    scatter_kernel<<<(ETOT + 255) / 256, 256, 0, stream>>>(ei, cursor, csr_src);

    // ---- GAT layers ----
    dim3 gemm_grid(HC / 64, (Nn + 63) / 64);
    for (int l = 0; l < Ll; ++l) {
        const float* in_feat = (l == 0) ? x : h2;
        int K = (l == 0) ? Dd : HC;
        const float* Wl = (l == 0) ? W0 : (W_rest + (size_t)(l - 1) * HC * HC);
        gemm_kernel<<<gemm_grid, 256, 0, stream>>>(in_feat, Wl, h1, Nn, K);
        alpha_kernel<<<Nn, 256, 0, stream>>>(h1, att_src + l * HC, att_dst + l * HC, asrc, adst);
        agg_kernel<<<dim3(Nn, Hh), 256, 0, stream>>>(h1, asrc, adst, row_ptr, csr_src,
                                                     conv_bias + l * HC, h2);
    }

    // ---- pool + proj + layernorm ----
    hipMemsetAsync(pooled, 0, (size_t)Bb * HC * 4, stream);
    hipMemsetAsync(counts, 0, (size_t)Bb * 4, stream);
    pool_kernel<<<Nn, 256, 0, stream>>>(h2, batch, pooled, counts);
    final_kernel<<<Bb, 512, 0, stream>>>(pooled, counts, proj_W, proj_b,
                                         ln_gamma, ln_beta, out);
}

// Round 2
// 1612.841 us; speedup vs baseline: 2.5628x; 2.5628x over previous
//
#include <hip/hip_runtime.h>
#include <hip/hip_bf16.h>
#include <math.h>

#define Nn 20000
#define Ee 320000
#define Dd 512
#define Hh 4
#define Cc 256
#define Ll 4
#define Bb 16
#define HC 1024               // H*C
#define ETOT (Ee + Nn)        // edges + self loops = 340000
#define NEG_SLOPE 0.2f
#define LN_EPS 1e-5f

typedef __attribute__((ext_vector_type(8))) __bf16 bf16x8;
typedef __attribute__((ext_vector_type(4))) float f32x4;

// ---------------- CSR build ----------------

__device__ __forceinline__ void decode_edge(const int* ei, int e, int& s, int& d) {
    if (e < Ee) { s = ei[e]; d = ei[Ee + e]; }
    else        { s = e - Ee; d = e - Ee; }   // self loop
}

__global__ void count_deg_kernel(const int* __restrict__ ei, int* __restrict__ deg) {
    int e = blockIdx.x * blockDim.x + threadIdx.x;
    if (e >= ETOT) return;
    int s, d; decode_edge(ei, e, s, d);
    atomicAdd(&deg[d], 1);
}

__global__ void scan_kernel(const int* __restrict__ deg, int* __restrict__ row_ptr) {
    __shared__ int sdata[1024];
    __shared__ int carry;
    int tid = threadIdx.x;
    if (tid == 0) { carry = 0; row_ptr[0] = 0; }
    __syncthreads();
    for (int base = 0; base < Nn; base += 1024) {
        int i = base + tid;
        int v = (i < Nn) ? deg[i] : 0;
        sdata[tid] = v;
        __syncthreads();
        for (int off = 1; off < 1024; off <<= 1) {
            int t = (tid >= off) ? sdata[tid - off] : 0;
            __syncthreads();
            sdata[tid] += t;
            __syncthreads();
        }
        if (i < Nn) row_ptr[i + 1] = carry + sdata[tid];
        __syncthreads();
        if (tid == 1023) carry += sdata[1023];
        __syncthreads();
    }
}

__global__ void cursor_init_kernel(const int* __restrict__ row_ptr, int* __restrict__ cursor) {
    int i = blockIdx.x * blockDim.x + threadIdx.x;
    if (i < Nn) cursor[i] = row_ptr[i];
}

__global__ void scatter_kernel(const int* __restrict__ ei, int* __restrict__ cursor,
                               int* __restrict__ csr_src) {
    int e = blockIdx.x * blockDim.x + threadIdx.x;
    if (e >= ETOT) return;
    int s, d; decode_edge(ei, e, s, d);
    int pos = atomicAdd(&cursor[d], 1);
    csr_src[pos] = s;
}

// ---------------- casts ----------------

__global__ void cast_kernel(const float* __restrict__ in, __bf16* __restrict__ out, int n) {
    int i = blockIdx.x * blockDim.x + threadIdx.x;
    if (i < n) out[i] = (__bf16)in[i];
}

// W[K][N] fp32 -> WT[N][K] bf16
__global__ void transpose_cast_kernel(const float* __restrict__ W, __bf16* __restrict__ WT,
                                      int K, int N) {
    __shared__ float tile[32][33];
    int n0 = blockIdx.x * 32, k0 = blockIdx.y * 32;
    for (int i = threadIdx.y; i < 32; i += 8)
        tile[i][threadIdx.x] = W[(size_t)(k0 + i) * N + n0 + threadIdx.x];
    __syncthreads();
    for (int i = threadIdx.y; i < 32; i += 8)
        WT[(size_t)(n0 + i) * K + k0 + threadIdx.x] = (__bf16)tile[threadIdx.x][i];
}

// ---------------- MFMA GEMM: C[M,1024] = A[M,K](bf16) @ BT[1024,K]^T (bf16) ----------------
// 128x128 tile, 4 waves, 16x16x32 bf16 MFMA, global_load_lds staging w/ XOR swizzle.

__device__ __forceinline__ void async16(const __bf16* g, __bf16* l) {
    __builtin_amdgcn_global_load_lds((const __attribute__((address_space(1))) void*)g,
                                     (__attribute__((address_space(3))) void*)l,
                                     16, 0, 0);
}

__global__ __launch_bounds__(256) void mfma_gemm_kernel(
    const __bf16* __restrict__ A,   // [M][K]
    const __bf16* __restrict__ BT,  // [1024][K]  (W transposed)
    float* __restrict__ C,          // [M][1024]
    int M, int K)
{
    __shared__ __bf16 As[128 * 32];   // [row][32], chunk-swizzled
    __shared__ __bf16 Bs[128 * 32];   // [col][32], chunk-swizzled
    int tid = threadIdx.x;
    int wave = tid >> 6, lane = tid & 63;
    int m16 = lane & 15, quad = lane >> 4;
    int rowBase = blockIdx.y * 128, colBase = blockIdx.x * 128;
    int waveRow = (wave >> 1) * 64, waveCol = (wave & 1) * 64;

    f32x4 acc[4][4] = {};

    for (int k0 = 0; k0 < K; k0 += 32) {
        #pragma unroll
        for (int L = 0; L < 2; ++L) {
            int row = wave * 32 + L * 16 + (lane >> 2);       // 0..127
            int gch = (lane & 3) ^ ((row >> 1) & 3);          // XOR swizzle
            int gr = rowBase + row; if (gr >= M) gr = M - 1;  // clamp tail rows
            async16(A + (size_t)gr * K + k0 + gch * 8,
                    &As[(wave * 32 + L * 16) * 32 + lane * 8]);
            async16(BT + (size_t)(colBase + row) * K + k0 + gch * 8,
                    &Bs[(wave * 32 + L * 16) * 32 + lane * 8]);
        }
        __syncthreads();   // drains vmcnt (global_load_lds) + barrier
        bf16x8 af[4], bfr[4];
        #pragma unroll
        for (int i = 0; i < 4; ++i) {
            int row = waveRow + i * 16 + m16;
            af[i] = *(const bf16x8*)&As[row * 32 + (quad ^ ((row >> 1) & 3)) * 8];
            int col = waveCol + i * 16 + m16;
            bfr[i] = *(const bf16x8*)&Bs[col * 32 + (quad ^ ((col >> 1) & 3)) * 8];
        }
        #pragma unroll
        for (int i = 0; i < 4; ++i)
            #pragma unroll
            for (int j = 0; j < 4; ++j)
                acc[i][j] = __builtin_amdgcn_mfma_f32_16x16x32_bf16(af[i], bfr[j], acc[i][j], 0, 0, 0);
        __syncthreads();
    }

    // epilogue: C/D layout col=lane&15, row=quad*4+reg
    #pragma unroll
    for (int i = 0; i < 4; ++i) {
        int r0 = rowBase + waveRow + i * 16 + quad * 4;
        #pragma unroll
        for (int j = 0; j < 4; ++j) {
            int c = colBase + waveCol + j * 16 + m16;
            #pragma unroll
            for (int r = 0; r < 4; ++r)
                if (r0 + r < M) C[(size_t)(r0 + r) * HC + c] = acc[i][j][r];
        }
    }
}

// ---------------- attention logits per node/head ----------------

__global__ void alpha_kernel(const float* __restrict__ hfeat,
                             const float* __restrict__ att_src_l,
                             const float* __restrict__ att_dst_l,
                             float* __restrict__ asrc, float* __restrict__ adst) {
    int n = blockIdx.x;
    int hh = threadIdx.x >> 6;
    int lane = threadIdx.x & 63;
    float s1 = 0.f, s2 = 0.f;
    #pragma unroll
    for (int c = lane; c < Cc; c += 64) {
        float v = hfeat[(size_t)n * HC + hh * Cc + c];
        s1 += v * att_src_l[hh * Cc + c];
        s2 += v * att_dst_l[hh * Cc + c];
    }
    #pragma unroll
    for (int off = 32; off > 0; off >>= 1) {
        s1 += __shfl_down(s1, off);
        s2 += __shfl_down(s2, off);
    }
    if (lane == 0) {
        asrc[n * Hh + hh] = s1;
        adst[n * Hh + hh] = s2;
    }
}

// ---------------- softmax-weighted aggregation ----------------
// one block per (node, head); weights precomputed per 64-edge chunk in LDS.

__global__ __launch_bounds__(256) void agg_kernel(const float* __restrict__ hfeat,
                                                  const float* __restrict__ asrc,
                                                  const float* __restrict__ adst,
                                                  const int* __restrict__ row_ptr,
                                                  const int* __restrict__ csr_src,
                                                  const float* __restrict__ bias_l,
                                                  __bf16* __restrict__ outb) {
    int n = blockIdx.x, hh = blockIdx.y;
    int tid = threadIdx.x;
    int start = row_ptr[n], end = row_ptr[n + 1];
    float adst_n = adst[n * Hh + hh];
    __shared__ float red[256];
    __shared__ float wsh[64];
    __shared__ int ssh[64];

    // phase 1: segment max
    float mx = -INFINITY;
    for (int e = start + tid; e < end; e += 256) {
        int s = csr_src[e];
        float z = asrc[s * Hh + hh] + adst_n;
        z = (z > 0.f) ? z : NEG_SLOPE * z;
        mx = fmaxf(mx, z);
    }
    red[tid] = mx;
    __syncthreads();
    for (int off = 128; off > 0; off >>= 1) {
        if (tid < off) red[tid] = fmaxf(red[tid], red[tid + off]);
        __syncthreads();
    }
    float m = red[0];
    __syncthreads();

    // phase 2: denom
    float sm = 0.f;
    for (int e = start + tid; e < end; e += 256) {
        int s = csr_src[e];
        float z = asrc[s * Hh + hh] + adst_n;
        z = (z > 0.f) ? z : NEG_SLOPE * z;
        sm += expf(z - m);
    }
    red[tid] = sm;
    __syncthreads();
    for (int off = 128; off > 0; off >>= 1) {
        if (tid < off) red[tid] += red[tid + off];
        __syncthreads();
    }
    float inv = 1.0f / (red[0] + 1e-16f);
    __syncthreads();

    // phase 3: weighted accumulate, channel c = tid
    float acc = 0.f;
    for (int base = start; base < end; base += 64) {
        int cnt = min(64, end - base);
        if (tid < cnt) {
            int s = csr_src[base + tid];
            float z = asrc[s * Hh + hh] + adst_n;
            z = (z > 0.f) ? z : NEG_SLOPE * z;
            wsh[tid] = expf(z - m) * inv;
            ssh[tid] = s;
        }
        __syncthreads();
        for (int e = 0; e < cnt; ++e)
            acc += wsh[e] * hfeat[(size_t)ssh[e] * HC + hh * Cc + tid];
        __syncthreads();
    }
    float v = acc + bias_l[hh * Cc + tid];
    outb[(size_t)n * HC + hh * Cc + tid] = (__bf16)fmaxf(v, 0.f);   // relu + bf16 for next GEMM
}

// ---------------- global mean pool (batch is sorted -> contiguous ranges) ----------------

__device__ __forceinline__ int lower_bound_batch(const int* __restrict__ batch, int val) {
    int lo = 0, hi = Nn;
    while (lo < hi) { int mid = (lo + hi) >> 1; if (batch[mid] < val) lo = mid + 1; else hi = mid; }
    return lo;
}

__global__ void pool_kernel(const __bf16* __restrict__ h2b, const int* __restrict__ batch,
                            float* __restrict__ pooled) {
    int b = blockIdx.x, part = blockIdx.y;   // grid (B, 8)
    int tid = threadIdx.x;
    int start = lower_bound_batch(batch, b);
    int end   = lower_bound_batch(batch, b + 1);
    int len = end - start;
    int chunk = (len + 7) / 8;
    int s0 = start + part * chunk;
    int s1 = min(s0 + chunk, end);
    float acc[4] = {0.f, 0.f, 0.f, 0.f};
    for (int n = s0; n < s1; ++n)
        #pragma unroll
        for (int k = 0; k < 4; ++k)
            acc[k] += (float)h2b[(size_t)n * HC + k * 256 + tid];
    #pragma unroll
    for (int k = 0; k < 4; ++k)
        atomicAdd(&pooled[b * HC + k * 256 + tid], acc[k]);
}

// ---------------- projection + layernorm ----------------

__global__ __launch_bounds__(512) void final_kernel(const float* __restrict__ pooled,
                                                    const int* __restrict__ batch,
                                                    const float* __restrict__ projW,
                                                    const float* __restrict__ projb,
                                                    const float* __restrict__ gamma,
                                                    const float* __restrict__ beta,
                                                    float* __restrict__ out) {
    int b = blockIdx.x;
    int d = threadIdx.x;           // 512 threads
    __shared__ float p[HC];
    __shared__ float red[512];
    int start = lower_bound_batch(batch, b);
    int end   = lower_bound_batch(batch, b + 1);
    float inv = 1.0f / fmaxf((float)(end - start), 1.0f);
    for (int k = d; k < HC; k += 512) p[k] = pooled[b * HC + k] * inv;
    __syncthreads();
    float o = projb[d];
    for (int k = 0; k < HC; ++k) o += p[k] * projW[(size_t)k * Dd + d];
    red[d] = o;
    __syncthreads();
    for (int off = 256; off > 0; off >>= 1) {
        if (d < off) red[d] += red[d + off];
        __syncthreads();
    }
    float mu = red[0] / (float)Dd;
    __syncthreads();
    float df = o - mu;
    red[d] = df * df;
    __syncthreads();
    for (int off = 256; off > 0; off >>= 1) {
        if (d < off) red[d] += red[d + off];
        __syncthreads();
    }
    float var = red[0] / (float)Dd;
    out[b * Dd + d] = df / sqrtf(var + LN_EPS) * gamma[d] + beta[d];
}

// ---------------- launch ----------------

extern "C" void kernel_launch(void* const* d_in, const int* in_sizes, int n_in,
                              void* d_out, int out_size, void* d_ws, size_t ws_size,
                              hipStream_t stream) {
    const float* x         = (const float*)d_in[0];
    const int*   ei        = (const int*)d_in[1];
    const int*   batch     = (const int*)d_in[2];
    const float* W0        = (const float*)d_in[3];
    const float* W_rest    = (const float*)d_in[4];
    const float* att_src   = (const float*)d_in[5];
    const float* att_dst   = (const float*)d_in[6];
    const float* conv_bias = (const float*)d_in[7];
    const float* proj_W    = (const float*)d_in[8];
    const float* proj_b    = (const float*)d_in[9];
    const float* ln_gamma  = (const float*)d_in[10];
    const float* ln_beta   = (const float*)d_in[11];
    float* out = (float*)d_out;

    char* ws = (char*)d_ws;
    size_t off = 0;
    auto alloc = [&](size_t bytes) {
        void* p = ws + off;
        off = (off + bytes + 255) & ~(size_t)255;
        return p;
    };
    float*  h1      = (float*)alloc((size_t)Nn * HC * 4);    // GEMM out (fp32)
    __bf16* h2b     = (__bf16*)alloc((size_t)Nn * HC * 2);   // layer out (bf16)
    __bf16* xb      = (__bf16*)alloc((size_t)Nn * Dd * 2);   // x cast
    __bf16* W0T     = (__bf16*)alloc((size_t)HC * Dd * 2);   // [1024][512]
    __bf16* WrT     = (__bf16*)alloc((size_t)3 * HC * HC * 2);
    float*  asrc    = (float*)alloc((size_t)Nn * Hh * 4);
    float*  adst    = (float*)alloc((size_t)Nn * Hh * 4);
    int*    deg     = (int*)alloc((size_t)Nn * 4);
    int*    row_ptr = (int*)alloc((size_t)(Nn + 1) * 4);
    int*    cursor  = (int*)alloc((size_t)Nn * 4);
    int*    csr_src = (int*)alloc((size_t)ETOT * 4);
    float*  pooled  = (float*)alloc((size_t)Bb * HC * 4);
    (void)ws_size; (void)in_sizes; (void)n_in; (void)out_size;

    // ---- build CSR by destination ----
    hipMemsetAsync(deg, 0, (size_t)Nn * 4, stream);
    count_deg_kernel<<<(ETOT + 255) / 256, 256, 0, stream>>>(ei, deg);
    scan_kernel<<<1, 1024, 0, stream>>>(deg, row_ptr);
    cursor_init_kernel<<<(Nn + 255) / 256, 256, 0, stream>>>(row_ptr, cursor);
    scatter_kernel<<<(ETOT + 255) / 256, 256, 0, stream>>>(ei, cursor, csr_src);

    // ---- bf16 casts / weight transposes ----
    cast_kernel<<<(Nn * Dd + 255) / 256, 256, 0, stream>>>(x, xb, Nn * Dd);
    transpose_cast_kernel<<<dim3(HC / 32, Dd / 32), dim3(32, 8), 0, stream>>>(W0, W0T, Dd, HC);
    for (int l = 0; l < 3; ++l)
        transpose_cast_kernel<<<dim3(HC / 32, HC / 32), dim3(32, 8), 0, stream>>>(
            W_rest + (size_t)l * HC * HC, WrT + (size_t)l * HC * HC, HC, HC);

    // ---- GAT layers ----
    dim3 gemm_grid(HC / 128, (Nn + 127) / 128);   // (8, 157)
    for (int l = 0; l < Ll; ++l) {
        const __bf16* Afeat = (l == 0) ? xb : h2b;
        int K = (l == 0) ? Dd : HC;
        const __bf16* BT = (l == 0) ? W0T : (WrT + (size_t)(l - 1) * HC * HC);
        mfma_gemm_kernel<<<gemm_grid, 256, 0, stream>>>(Afeat, BT, h1, Nn, K);
        alpha_kernel<<<Nn, 256, 0, stream>>>(h1, att_src + l * HC, att_dst + l * HC, asrc, adst);
        agg_kernel<<<dim3(Nn, Hh), 256, 0, stream>>>(h1, asrc, adst, row_ptr, csr_src,
                                                     conv_bias + l * HC, h2b);
    }

    // ---- pool + proj + layernorm ----
    hipMemsetAsync(pooled, 0, (size_t)Bb * HC * 4, stream);
    pool_kernel<<<dim3(Bb, 8), 256, 0, stream>>>(h2b, batch, pooled);
    final_kernel<<<Bb, 512, 0, stream>>>(pooled, batch, proj_W, proj_b,
                                         ln_gamma, ln_beta, out);
}

// Round 3
// 986.399 us; speedup vs baseline: 4.1904x; 1.6351x over previous
//
#include <hip/hip_runtime.h>
#include <hip/hip_bf16.h>
#include <math.h>

#define Nn 20000
#define Ee 320000
#define Dd 512
#define Hh 4
#define Cc 256
#define Ll 4
#define Bb 16
#define HC 1024               // H*C
#define ETOT (Ee + Nn)        // edges + self loops = 340000
#define NEG_SLOPE 0.2f
#define LN_EPS 1e-5f
#define NBLK ((Nn + 255) / 256)   // 79 scan blocks

typedef __attribute__((ext_vector_type(8))) __bf16 bf16x8;
typedef __attribute__((ext_vector_type(4))) __bf16 bf16x4;
typedef __attribute__((ext_vector_type(4))) float f32x4;

// ---------------- CSR build ----------------

__device__ __forceinline__ void decode_edge(const int* ei, int e, int& s, int& d) {
    if (e < Ee) { s = ei[e]; d = ei[Ee + e]; }
    else        { s = e - Ee; d = e - Ee; }   // self loop
}

__global__ void count_deg_kernel(const int* __restrict__ ei, int* __restrict__ deg) {
    int e = blockIdx.x * blockDim.x + threadIdx.x;
    if (e >= ETOT) return;
    int s, d; decode_edge(ei, e, s, d);
    atomicAdd(&deg[d], 1);
}

// hierarchical scan: per-256-chunk inclusive scan + block sums
__global__ void scan1_kernel(const int* __restrict__ deg, int* __restrict__ tmp,
                             int* __restrict__ bsum) {
    __shared__ int sd[256];
    int tid = threadIdx.x;
    int i = blockIdx.x * 256 + tid;
    sd[tid] = (i < Nn) ? deg[i] : 0;
    __syncthreads();
    for (int off = 1; off < 256; off <<= 1) {
        int t = (tid >= off) ? sd[tid - off] : 0;
        __syncthreads();
        sd[tid] += t;
        __syncthreads();
    }
    if (i < Nn) tmp[i] = sd[tid];
    if (tid == 255) bsum[blockIdx.x] = sd[255];
}

__global__ void scan2_kernel(int* __restrict__ bsum) {   // single block, NBLK<=256
    __shared__ int sd[256];
    int tid = threadIdx.x;
    sd[tid] = (tid < NBLK) ? bsum[tid] : 0;
    __syncthreads();
    for (int off = 1; off < 256; off <<= 1) {
        int t = (tid >= off) ? sd[tid - off] : 0;
        __syncthreads();
        sd[tid] += t;
        __syncthreads();
    }
    if (tid < NBLK) bsum[tid] = sd[tid];
}

__global__ void scan3_kernel(const int* __restrict__ tmp, const int* __restrict__ bsum,
                             const int* __restrict__ deg,
                             int* __restrict__ row_ptr, int* __restrict__ cursor) {
    int i = blockIdx.x * 256 + threadIdx.x;
    if (i >= Nn) return;
    int boff = (blockIdx.x == 0) ? 0 : bsum[blockIdx.x - 1];
    int incl = tmp[i] + boff;
    row_ptr[i + 1] = incl;
    cursor[i] = incl - deg[i];
    if (i == 0) row_ptr[0] = 0;
}

__global__ void scatter_kernel(const int* __restrict__ ei, int* __restrict__ cursor,
                               int* __restrict__ csr_src) {
    int e = blockIdx.x * blockDim.x + threadIdx.x;
    if (e >= ETOT) return;
    int s, d; decode_edge(ei, e, s, d);
    int pos = atomicAdd(&cursor[d], 1);
    csr_src[pos] = s;
}

// ---------------- casts ----------------

__global__ void cast_kernel(const float* __restrict__ in, __bf16* __restrict__ out, int n) {
    int i = blockIdx.x * blockDim.x + threadIdx.x;
    if (i < n) out[i] = (__bf16)in[i];
}

// W[K][N] fp32 -> WT[N][K] bf16
__global__ void transpose_cast_kernel(const float* __restrict__ W, __bf16* __restrict__ WT,
                                      int K, int N) {
    __shared__ float tile[32][33];
    int n0 = blockIdx.x * 32, k0 = blockIdx.y * 32;
    for (int i = threadIdx.y; i < 32; i += 8)
        tile[i][threadIdx.x] = W[(size_t)(k0 + i) * N + n0 + threadIdx.x];
    __syncthreads();
    for (int i = threadIdx.y; i < 32; i += 8)
        WT[(size_t)(n0 + i) * K + k0 + threadIdx.x] = (__bf16)tile[threadIdx.x][i];
}

// ---------------- MFMA GEMM: C[M,1024](bf16) = A[M,K](bf16) @ BT[1024,K]^T ----------------

__device__ __forceinline__ void async16(const __bf16* g, __bf16* l) {
    __builtin_amdgcn_global_load_lds((const __attribute__((address_space(1))) void*)g,
                                     (__attribute__((address_space(3))) void*)l,
                                     16, 0, 0);
}

__global__ __launch_bounds__(256) void mfma_gemm_kernel(
    const __bf16* __restrict__ A,   // [M][K]
    const __bf16* __restrict__ BT,  // [1024][K]
    __bf16* __restrict__ C,         // [M][1024]
    int M, int K)
{
    __shared__ __bf16 As[128 * 32];
    __shared__ __bf16 Bs[128 * 32];
    int tid = threadIdx.x;
    int wave = tid >> 6, lane = tid & 63;
    int m16 = lane & 15, quad = lane >> 4;
    int rowBase = blockIdx.y * 128, colBase = blockIdx.x * 128;
    int waveRow = (wave >> 1) * 64, waveCol = (wave & 1) * 64;

    f32x4 acc[4][4] = {};

    for (int k0 = 0; k0 < K; k0 += 32) {
        #pragma unroll
        for (int L = 0; L < 2; ++L) {
            int row = wave * 32 + L * 16 + (lane >> 2);
            int gch = (lane & 3) ^ ((row >> 1) & 3);
            int gr = rowBase + row; if (gr >= M) gr = M - 1;
            async16(A + (size_t)gr * K + k0 + gch * 8,
                    &As[(wave * 32 + L * 16) * 32 + lane * 8]);
            async16(BT + (size_t)(colBase + row) * K + k0 + gch * 8,
                    &Bs[(wave * 32 + L * 16) * 32 + lane * 8]);
        }
        __syncthreads();
        bf16x8 af[4], bfr[4];
        #pragma unroll
        for (int i = 0; i < 4; ++i) {
            int row = waveRow + i * 16 + m16;
            af[i] = *(const bf16x8*)&As[row * 32 + (quad ^ ((row >> 1) & 3)) * 8];
            int col = waveCol + i * 16 + m16;
            bfr[i] = *(const bf16x8*)&Bs[col * 32 + (quad ^ ((col >> 1) & 3)) * 8];
        }
        #pragma unroll
        for (int i = 0; i < 4; ++i)
            #pragma unroll
            for (int j = 0; j < 4; ++j)
                acc[i][j] = __builtin_amdgcn_mfma_f32_16x16x32_bf16(af[i], bfr[j], acc[i][j], 0, 0, 0);
        __syncthreads();
    }

    #pragma unroll
    for (int i = 0; i < 4; ++i) {
        int r0 = rowBase + waveRow + i * 16 + quad * 4;
        #pragma unroll
        for (int j = 0; j < 4; ++j) {
            int c = colBase + waveCol + j * 16 + m16;
            #pragma unroll
            for (int r = 0; r < 4; ++r)
                if (r0 + r < M) C[(size_t)(r0 + r) * HC + c] = (__bf16)acc[i][j][r];
        }
    }
}

// ---------------- attention logits per node/head ----------------
// wave h computes head h; lane covers 4 contiguous channels.

__global__ void alpha_kernel(const __bf16* __restrict__ hb,
                             const float* __restrict__ att_src_l,
                             const float* __restrict__ att_dst_l,
                             float* __restrict__ asrc, float* __restrict__ adst) {
    int n = blockIdx.x;
    int wave = threadIdx.x >> 6;
    int lane = threadIdx.x & 63;
    bf16x4 v = ((const bf16x4*)(hb + (size_t)n * HC + wave * Cc))[lane];
    f32x4 w1 = ((const f32x4*)(att_src_l + wave * Cc))[lane];
    f32x4 w2 = ((const f32x4*)(att_dst_l + wave * Cc))[lane];
    float s1 = 0.f, s2 = 0.f;
    #pragma unroll
    for (int k = 0; k < 4; ++k) {
        float f = (float)v[k];
        s1 += f * w1[k];
        s2 += f * w2[k];
    }
    #pragma unroll
    for (int off = 32; off > 0; off >>= 1) {
        s1 += __shfl_down(s1, off);
        s2 += __shfl_down(s2, off);
    }
    if (lane == 0) {
        asrc[n * Hh + wave] = s1;
        adst[n * Hh + wave] = s2;
    }
}

// ---------------- softmax-weighted aggregation ----------------
// one block per node, all 4 heads. Wave h owns head h (shuffle reductions only).
// Thread t gathers channels [4t, 4t+4) (its head = t>>6 = its wave).

__global__ __launch_bounds__(256) void agg_kernel(const __bf16* __restrict__ hb,
                                                  const float* __restrict__ asrc,
                                                  const float* __restrict__ adst,
                                                  const int* __restrict__ row_ptr,
                                                  const int* __restrict__ csr_src,
                                                  const float* __restrict__ bias_l,
                                                  __bf16* __restrict__ outb) {
    int n = blockIdx.x;
    int tid = threadIdx.x;
    int wave = tid >> 6, lane = tid & 63;
    int start = row_ptr[n], end = row_ptr[n + 1];

    __shared__ float m_sh[4], inv_sh[4], adst_sh[4];
    __shared__ float wsh[256];   // [edge_in_chunk][head]
    __shared__ int ssh[64];

    if (tid < 4) adst_sh[tid] = adst[n * Hh + tid];
    float adst_n = adst[n * Hh + wave];

    // segment max (wave-local, head = wave)
    float mx = -INFINITY;
    for (int e = start + lane; e < end; e += 64) {
        int s = csr_src[e];
        float z = asrc[s * Hh + wave] + adst_n;
        z = (z > 0.f) ? z : NEG_SLOPE * z;
        mx = fmaxf(mx, z);
    }
    #pragma unroll
    for (int off = 32; off > 0; off >>= 1) mx = fmaxf(mx, __shfl_down(mx, off));
    mx = __shfl(mx, 0);

    // denom
    float sm = 0.f;
    for (int e = start + lane; e < end; e += 64) {
        int s = csr_src[e];
        float z = asrc[s * Hh + wave] + adst_n;
        z = (z > 0.f) ? z : NEG_SLOPE * z;
        sm += __expf(z - mx);
    }
    #pragma unroll
    for (int off = 32; off > 0; off >>= 1) sm += __shfl_down(sm, off);
    if (lane == 0) { m_sh[wave] = mx; inv_sh[wave] = 1.f / (sm + 1e-16f); }
    __syncthreads();

    // gather, 64-edge chunks; weights for all 4 heads computed by 4*cnt threads
    float acc[4] = {0.f, 0.f, 0.f, 0.f};
    for (int base = start; base < end; base += 64) {
        int cnt = min(64, end - base);
        int eidx = tid >> 2, hh = tid & 3;
        if (eidx < cnt) {
            int s = csr_src[base + eidx];
            if (hh == 0) ssh[eidx] = s;
            float z = asrc[s * Hh + hh] + adst_sh[hh];
            z = (z > 0.f) ? z : NEG_SLOPE * z;
            wsh[eidx * 4 + hh] = __expf(z - m_sh[hh]) * inv_sh[hh];
        }
        __syncthreads();
        int e = 0;
        for (; e + 2 <= cnt; e += 2) {
            bf16x4 v0 = ((const bf16x4*)(hb + (size_t)ssh[e] * HC))[tid];
            bf16x4 v1 = ((const bf16x4*)(hb + (size_t)ssh[e + 1] * HC))[tid];
            float w0 = wsh[e * 4 + wave], w1 = wsh[(e + 1) * 4 + wave];
            #pragma unroll
            for (int k = 0; k < 4; ++k) acc[k] += w0 * (float)v0[k];
            #pragma unroll
            for (int k = 0; k < 4; ++k) acc[k] += w1 * (float)v1[k];
        }
        if (e < cnt) {
            bf16x4 v0 = ((const bf16x4*)(hb + (size_t)ssh[e] * HC))[tid];
            float w0 = wsh[e * 4 + wave];
            #pragma unroll
            for (int k = 0; k < 4; ++k) acc[k] += w0 * (float)v0[k];
        }
        __syncthreads();
    }

    bf16x4 o;
    #pragma unroll
    for (int k = 0; k < 4; ++k)
        o[k] = (__bf16)fmaxf(acc[k] + bias_l[tid * 4 + k], 0.f);   // bias + relu
    ((bf16x4*)(outb + (size_t)n * HC))[tid] = o;
}

// ---------------- global mean pool (batch sorted -> contiguous ranges) ----------------

__device__ __forceinline__ int lower_bound_batch(const int* __restrict__ batch, int val) {
    int lo = 0, hi = Nn;
    while (lo < hi) { int mid = (lo + hi) >> 1; if (batch[mid] < val) lo = mid + 1; else hi = mid; }
    return lo;
}

__global__ void pool_kernel(const __bf16* __restrict__ h2b, const int* __restrict__ batch,
                            float* __restrict__ pooled) {
    int b = blockIdx.x, part = blockIdx.y;   // grid (B, 8)
    int tid = threadIdx.x;
    int start = lower_bound_batch(batch, b);
    int end   = lower_bound_batch(batch, b + 1);
    int len = end - start;
    int chunk = (len + 7) / 8;
    int s0 = start + part * chunk;
    int s1 = min(s0 + chunk, end);
    float acc[4] = {0.f, 0.f, 0.f, 0.f};
    for (int n = s0; n < s1; ++n) {
        bf16x4 v = ((const bf16x4*)(h2b + (size_t)n * HC))[tid];
        #pragma unroll
        for (int k = 0; k < 4; ++k) acc[k] += (float)v[k];
    }
    #pragma unroll
    for (int k = 0; k < 4; ++k)
        atomicAdd(&pooled[b * HC + tid * 4 + k], acc[k]);
}

// ---------------- projection + layernorm ----------------

__global__ __launch_bounds__(512) void final_kernel(const float* __restrict__ pooled,
                                                    const int* __restrict__ batch,
                                                    const float* __restrict__ projW,
                                                    const float* __restrict__ projb,
                                                    const float* __restrict__ gamma,
                                                    const float* __restrict__ beta,
                                                    float* __restrict__ out) {
    int b = blockIdx.x;
    int d = threadIdx.x;
    __shared__ float p[HC];
    __shared__ float red[512];
    int start = lower_bound_batch(batch, b);
    int end   = lower_bound_batch(batch, b + 1);
    float inv = 1.0f / fmaxf((float)(end - start), 1.0f);
    for (int k = d; k < HC; k += 512) p[k] = pooled[b * HC + k] * inv;
    __syncthreads();
    float o = projb[d];
    for (int k = 0; k < HC; ++k) o += p[k] * projW[(size_t)k * Dd + d];
    red[d] = o;
    __syncthreads();
    for (int off = 256; off > 0; off >>= 1) {
        if (d < off) red[d] += red[d + off];
        __syncthreads();
    }
    float mu = red[0] / (float)Dd;
    __syncthreads();
    float df = o - mu;
    red[d] = df * df;
    __syncthreads();
    for (int off = 256; off > 0; off >>= 1) {
        if (d < off) red[d] += red[d + off];
        __syncthreads();
    }
    float var = red[0] / (float)Dd;
    out[b * Dd + d] = df / sqrtf(var + LN_EPS) * gamma[d] + beta[d];
}

// ---------------- launch ----------------

extern "C" void kernel_launch(void* const* d_in, const int* in_sizes, int n_in,
                              void* d_out, int out_size, void* d_ws, size_t ws_size,
                              hipStream_t stream) {
    const float* x         = (const float*)d_in[0];
    const int*   ei        = (const int*)d_in[1];
    const int*   batch     = (const int*)d_in[2];
    const float* W0        = (const float*)d_in[3];
    const float* W_rest    = (const float*)d_in[4];
    const float* att_src   = (const float*)d_in[5];
    const float* att_dst   = (const float*)d_in[6];
    const float* conv_bias = (const float*)d_in[7];
    const float* proj_W    = (const float*)d_in[8];
    const float* proj_b    = (const float*)d_in[9];
    const float* ln_gamma  = (const float*)d_in[10];
    const float* ln_beta   = (const float*)d_in[11];
    float* out = (float*)d_out;

    char* ws = (char*)d_ws;
    size_t off = 0;
    auto alloc = [&](size_t bytes) {
        void* p = ws + off;
        off = (off + bytes + 255) & ~(size_t)255;
        return p;
    };
    __bf16* h1b     = (__bf16*)alloc((size_t)Nn * HC * 2);   // GEMM out (bf16)
    __bf16* h2b     = (__bf16*)alloc((size_t)Nn * HC * 2);   // layer out (bf16)
    __bf16* xb      = (__bf16*)alloc((size_t)Nn * Dd * 2);
    __bf16* W0T     = (__bf16*)alloc((size_t)HC * Dd * 2);
    __bf16* WrT     = (__bf16*)alloc((size_t)3 * HC * HC * 2);
    float*  asrc    = (float*)alloc((size_t)Nn * Hh * 4);
    float*  adst    = (float*)alloc((size_t)Nn * Hh * 4);
    int*    deg     = (int*)alloc((size_t)Nn * 4);
    int*    tmp     = (int*)alloc((size_t)Nn * 4);
    int*    bsum    = (int*)alloc((size_t)256 * 4);
    int*    row_ptr = (int*)alloc((size_t)(Nn + 1) * 4);
    int*    cursor  = (int*)alloc((size_t)Nn * 4);
    int*    csr_src = (int*)alloc((size_t)ETOT * 4);
    float*  pooled  = (float*)alloc((size_t)Bb * HC * 4);
    (void)ws_size; (void)in_sizes; (void)n_in; (void)out_size;

    // ---- build CSR by destination ----
    hipMemsetAsync(deg, 0, (size_t)Nn * 4, stream);
    count_deg_kernel<<<(ETOT + 255) / 256, 256, 0, stream>>>(ei, deg);
    scan1_kernel<<<NBLK, 256, 0, stream>>>(deg, tmp, bsum);
    scan2_kernel<<<1, 256, 0, stream>>>(bsum);
    scan3_kernel<<<NBLK, 256, 0, stream>>>(tmp, bsum, deg, row_ptr, cursor);
    scatter_kernel<<<(ETOT + 255) / 256, 256, 0, stream>>>(ei, cursor, csr_src);

    // ---- bf16 casts / weight transposes ----
    cast_kernel<<<(Nn * Dd + 255) / 256, 256, 0, stream>>>(x, xb, Nn * Dd);
    transpose_cast_kernel<<<dim3(HC / 32, Dd / 32), dim3(32, 8), 0, stream>>>(W0, W0T, Dd, HC);
    for (int l = 0; l < 3; ++l)
        transpose_cast_kernel<<<dim3(HC / 32, HC / 32), dim3(32, 8), 0, stream>>>(
            W_rest + (size_t)l * HC * HC, WrT + (size_t)l * HC * HC, HC, HC);

    // ---- GAT layers ----
    dim3 gemm_grid(HC / 128, (Nn + 127) / 128);   // (8, 157)
    for (int l = 0; l < Ll; ++l) {
        const __bf16* Afeat = (l == 0) ? xb : h2b;
        int K = (l == 0) ? Dd : HC;
        const __bf16* BT = (l == 0) ? W0T : (WrT + (size_t)(l - 1) * HC * HC);
        mfma_gemm_kernel<<<gemm_grid, 256, 0, stream>>>(Afeat, BT, h1b, Nn, K);
        alpha_kernel<<<Nn, 256, 0, stream>>>(h1b, att_src + l * HC, att_dst + l * HC, asrc, adst);
        agg_kernel<<<Nn, 256, 0, stream>>>(h1b, asrc, adst, row_ptr, csr_src,
                                           conv_bias + l * HC, h2b);
    }

    // ---- pool + proj + layernorm ----
    hipMemsetAsync(pooled, 0, (size_t)Bb * HC * 4, stream);
    pool_kernel<<<dim3(Bb, 8), 256, 0, stream>>>(h2b, batch, pooled);
    final_kernel<<<Bb, 512, 0, stream>>>(pooled, batch, proj_W, proj_b,
                                         ln_gamma, ln_beta, out);
}

// Round 4
// 944.873 us; speedup vs baseline: 4.3746x; 1.0439x over previous
//
#include <hip/hip_runtime.h>
#include <hip/hip_bf16.h>
#include <math.h>

#define Nn 20000
#define Ee 320000
#define Dd 512
#define Hh 4
#define Cc 256
#define Ll 4
#define Bb 16
#define HC 1024               // H*C
#define ETOT (Ee + Nn)        // edges + self loops = 340000
#define NEG_SLOPE 0.2f
#define LN_EPS 1e-5f
#define NBLK ((Nn + 255) / 256)   // 79 scan blocks

typedef __attribute__((ext_vector_type(8))) __bf16 bf16x8;
typedef __attribute__((ext_vector_type(4))) __bf16 bf16x4;
typedef __attribute__((ext_vector_type(4))) float f32x4;

// ---------------- CSR build ----------------

__device__ __forceinline__ void decode_edge(const int* ei, int e, int& s, int& d) {
    if (e < Ee) { s = ei[e]; d = ei[Ee + e]; }
    else        { s = e - Ee; d = e - Ee; }   // self loop
}

__global__ void count_deg_kernel(const int* __restrict__ ei, int* __restrict__ deg) {
    int e = blockIdx.x * blockDim.x + threadIdx.x;
    if (e >= ETOT) return;
    int s, d; decode_edge(ei, e, s, d);
    atomicAdd(&deg[d], 1);
}

__global__ void scan1_kernel(const int* __restrict__ deg, int* __restrict__ tmp,
                             int* __restrict__ bsum) {
    __shared__ int sd[256];
    int tid = threadIdx.x;
    int i = blockIdx.x * 256 + tid;
    sd[tid] = (i < Nn) ? deg[i] : 0;
    __syncthreads();
    for (int off = 1; off < 256; off <<= 1) {
        int t = (tid >= off) ? sd[tid - off] : 0;
        __syncthreads();
        sd[tid] += t;
        __syncthreads();
    }
    if (i < Nn) tmp[i] = sd[tid];
    if (tid == 255) bsum[blockIdx.x] = sd[255];
}

__global__ void scan2_kernel(int* __restrict__ bsum) {   // single block, NBLK<=256
    __shared__ int sd[256];
    int tid = threadIdx.x;
    sd[tid] = (tid < NBLK) ? bsum[tid] : 0;
    __syncthreads();
    for (int off = 1; off < 256; off <<= 1) {
        int t = (tid >= off) ? sd[tid - off] : 0;
        __syncthreads();
        sd[tid] += t;
        __syncthreads();
    }
    if (tid < NBLK) bsum[tid] = sd[tid];
}

__global__ void scan3_kernel(const int* __restrict__ tmp, const int* __restrict__ bsum,
                             const int* __restrict__ deg,
                             int* __restrict__ row_ptr, int* __restrict__ cursor) {
    int i = blockIdx.x * 256 + threadIdx.x;
    if (i >= Nn) return;
    int boff = (blockIdx.x == 0) ? 0 : bsum[blockIdx.x - 1];
    int incl = tmp[i] + boff;
    row_ptr[i + 1] = incl;
    cursor[i] = incl - deg[i];
    if (i == 0) row_ptr[0] = 0;
}

__global__ void scatter_kernel(const int* __restrict__ ei, int* __restrict__ cursor,
                               int* __restrict__ csr_src) {
    int e = blockIdx.x * blockDim.x + threadIdx.x;
    if (e >= ETOT) return;
    int s, d; decode_edge(ei, e, s, d);
    int pos = atomicAdd(&cursor[d], 1);
    csr_src[pos] = s;
}

// ---------------- casts ----------------

__global__ void cast_kernel(const float* __restrict__ in, __bf16* __restrict__ out, int n4) {
    int i = blockIdx.x * blockDim.x + threadIdx.x;
    if (i >= n4) return;
    f32x4 v = ((const f32x4*)in)[i];
    bf16x4 o;
    #pragma unroll
    for (int k = 0; k < 4; ++k) o[k] = (__bf16)v[k];
    ((bf16x4*)out)[i] = o;
}

// W[K][N] fp32 -> WT[N][K] bf16
__global__ void transpose_cast_kernel(const float* __restrict__ W, __bf16* __restrict__ WT,
                                      int K, int N) {
    __shared__ float tile[32][33];
    int n0 = blockIdx.x * 32, k0 = blockIdx.y * 32;
    for (int i = threadIdx.y; i < 32; i += 8)
        tile[i][threadIdx.x] = W[(size_t)(k0 + i) * N + n0 + threadIdx.x];
    __syncthreads();
    for (int i = threadIdx.y; i < 32; i += 8)
        WT[(size_t)(n0 + i) * K + k0 + threadIdx.x] = (__bf16)tile[threadIdx.x][i];
}

// ---------------- MFMA GEMM + fused attention-logit epilogue ----------------
// C[M,1024](bf16) = A[M,K](bf16) @ BT[1024,K]^T, BK=64 (two 32-panels per barrier).
// Epilogue also accumulates asrc/adst partial dot products via atomics.

__device__ __forceinline__ void async16(const __bf16* g, __bf16* l) {
    __builtin_amdgcn_global_load_lds((const __attribute__((address_space(1))) void*)g,
                                     (__attribute__((address_space(3))) void*)l,
                                     16, 0, 0);
}

__global__ __launch_bounds__(256) void mfma_gemm_kernel(
    const __bf16* __restrict__ A,   // [M][K]
    const __bf16* __restrict__ BT,  // [1024][K]
    __bf16* __restrict__ C,         // [M][1024]
    const float* __restrict__ att_s,  // [4][256] this layer
    const float* __restrict__ att_d,  // [4][256]
    float* __restrict__ asrc,       // [M][4], pre-zeroed
    float* __restrict__ adst,       // [M][4], pre-zeroed
    int M, int K)
{
    __shared__ __bf16 As[2][128 * 32];
    __shared__ __bf16 Bs[2][128 * 32];
    int tid = threadIdx.x;
    int wave = tid >> 6, lane = tid & 63;
    int m16 = lane & 15, quad = lane >> 4;
    int rowBase = blockIdx.y * 128, colBase = blockIdx.x * 128;
    int waveRow = (wave >> 1) * 64, waveCol = (wave & 1) * 64;

    f32x4 acc[4][4] = {};

    int srow = wave * 32 + (lane >> 2);          // staging row, +16 for L=1
    int gch0 = (lane & 3) ^ ((srow >> 1) & 3);
    int gch1 = (lane & 3) ^ (((srow + 16) >> 1) & 3);
    int gr0 = rowBase + srow;       if (gr0 >= M) gr0 = M - 1;
    int gr1 = rowBase + srow + 16;  if (gr1 >= M) gr1 = M - 1;
    int ldsOff = srow * 32 + (lane & 3) * 8;

    for (int k0 = 0; k0 < K; k0 += 64) {
        #pragma unroll
        for (int p = 0; p < 2; ++p) {
            int kp = k0 + p * 32;
            async16(A + (size_t)gr0 * K + kp + gch0 * 8, &As[p][ldsOff]);
            async16(A + (size_t)gr1 * K + kp + gch1 * 8, &As[p][ldsOff + 16 * 32]);
            async16(BT + (size_t)(colBase + srow) * K + kp + gch0 * 8, &Bs[p][ldsOff]);
            async16(BT + (size_t)(colBase + srow + 16) * K + kp + gch1 * 8, &Bs[p][ldsOff + 16 * 32]);
        }
        __syncthreads();
        #pragma unroll
        for (int p = 0; p < 2; ++p) {
            bf16x8 af[4], bfr[4];
            #pragma unroll
            for (int i = 0; i < 4; ++i) {
                int row = waveRow + i * 16 + m16;
                af[i] = *(const bf16x8*)&As[p][row * 32 + (quad ^ ((row >> 1) & 3)) * 8];
                int col = waveCol + i * 16 + m16;
                bfr[i] = *(const bf16x8*)&Bs[p][col * 32 + (quad ^ ((col >> 1) & 3)) * 8];
            }
            #pragma unroll
            for (int i = 0; i < 4; ++i)
                #pragma unroll
                for (int j = 0; j < 4; ++j)
                    acc[i][j] = __builtin_amdgcn_mfma_f32_16x16x32_bf16(af[i], bfr[j], acc[i][j], 0, 0, 0);
        }
        __syncthreads();
    }

    // load att weights for this wave's 64-col span (single head)
    int cbase = colBase + waveCol;
    int head = cbase >> 8;
    float as4[4], ad4[4];
    #pragma unroll
    for (int j = 0; j < 4; ++j) {
        int off = (cbase + j * 16 + m16) & 255;
        as4[j] = att_s[head * 256 + off];
        ad4[j] = att_d[head * 256 + off];
    }

    // store C (bf16) + fused alpha partials
    #pragma unroll
    for (int i = 0; i < 4; ++i) {
        int r0 = rowBase + waveRow + i * 16 + quad * 4;
        #pragma unroll
        for (int r = 0; r < 4; ++r) {
            int row = r0 + r;
            float ps = 0.f, pd = 0.f;
            #pragma unroll
            for (int j = 0; j < 4; ++j) {
                float h = acc[i][j][r];
                ps += h * as4[j];
                pd += h * ad4[j];
                if (row < M)
                    C[(size_t)row * HC + colBase + waveCol + j * 16 + m16] = (__bf16)h;
            }
            #pragma unroll
            for (int off = 1; off < 16; off <<= 1) {
                ps += __shfl_xor(ps, off);
                pd += __shfl_xor(pd, off);
            }
            if (m16 == 0 && row < M) {
                atomicAdd(&asrc[row * Hh + head], ps);
                atomicAdd(&adst[row * Hh + head], pd);
            }
        }
    }
}

// ---------------- softmax-weighted aggregation ----------------
// one block per node, all 4 heads. No max-subtraction (shift-invariant, logits O(1)).

__global__ __launch_bounds__(256) void agg_kernel(const __bf16* __restrict__ hb,
                                                  const float* __restrict__ asrc,
                                                  const float* __restrict__ adst,
                                                  const int* __restrict__ row_ptr,
                                                  const int* __restrict__ csr_src,
                                                  const float* __restrict__ bias_l,
                                                  __bf16* __restrict__ outb) {
    int n = blockIdx.x;
    int tid = threadIdx.x;
    int wave = tid >> 6, lane = tid & 63;
    int start = row_ptr[n], end = row_ptr[n + 1];

    __shared__ float inv_sh[4], adst_sh[4];
    __shared__ float wsh[256];   // [edge_in_chunk][head]
    __shared__ int ssh[64];

    if (tid < 4) adst_sh[tid] = adst[n * Hh + tid];
    float adst_n = adst[n * Hh + wave];

    // denom (wave-local, head = wave)
    float sm = 0.f;
    for (int e = start + lane; e < end; e += 64) {
        int s = csr_src[e];
        float z = asrc[s * Hh + wave] + adst_n;
        z = (z > 0.f) ? z : NEG_SLOPE * z;
        sm += __expf(z);
    }
    #pragma unroll
    for (int off = 32; off > 0; off >>= 1) sm += __shfl_down(sm, off);
    if (lane == 0) inv_sh[wave] = 1.f / (sm + 1e-16f);
    __syncthreads();

    // gather, 64-edge chunks; weights for all 4 heads computed by 4*cnt threads
    float acc[4] = {0.f, 0.f, 0.f, 0.f};
    for (int base = start; base < end; base += 64) {
        int cnt = min(64, end - base);
        int eidx = tid >> 2, hh = tid & 3;
        if (eidx < cnt) {
            int s = csr_src[base + eidx];
            if (hh == 0) ssh[eidx] = s;
            float z = asrc[s * Hh + hh] + adst_sh[hh];
            z = (z > 0.f) ? z : NEG_SLOPE * z;
            wsh[eidx * 4 + hh] = __expf(z) * inv_sh[hh];
        }
        __syncthreads();
        int e = 0;
        for (; e + 4 <= cnt; e += 4) {
            bf16x4 v0 = ((const bf16x4*)(hb + (size_t)ssh[e] * HC))[tid];
            bf16x4 v1 = ((const bf16x4*)(hb + (size_t)ssh[e + 1] * HC))[tid];
            bf16x4 v2 = ((const bf16x4*)(hb + (size_t)ssh[e + 2] * HC))[tid];
            bf16x4 v3 = ((const bf16x4*)(hb + (size_t)ssh[e + 3] * HC))[tid];
            float w0 = wsh[e * 4 + wave], w1 = wsh[(e + 1) * 4 + wave];
            float w2 = wsh[(e + 2) * 4 + wave], w3 = wsh[(e + 3) * 4 + wave];
            #pragma unroll
            for (int k = 0; k < 4; ++k) {
                acc[k] += w0 * (float)v0[k];
                acc[k] += w1 * (float)v1[k];
                acc[k] += w2 * (float)v2[k];
                acc[k] += w3 * (float)v3[k];
            }
        }
        for (; e < cnt; ++e) {
            bf16x4 v0 = ((const bf16x4*)(hb + (size_t)ssh[e] * HC))[tid];
            float w0 = wsh[e * 4 + wave];
            #pragma unroll
            for (int k = 0; k < 4; ++k) acc[k] += w0 * (float)v0[k];
        }
        __syncthreads();
    }

    bf16x4 o;
    #pragma unroll
    for (int k = 0; k < 4; ++k)
        o[k] = (__bf16)fmaxf(acc[k] + bias_l[tid * 4 + k], 0.f);   // bias + relu
    ((bf16x4*)(outb + (size_t)n * HC))[tid] = o;
}

// ---------------- global mean pool (batch sorted -> contiguous ranges) ----------------

__device__ __forceinline__ int lower_bound_batch(const int* __restrict__ batch, int val) {
    int lo = 0, hi = Nn;
    while (lo < hi) { int mid = (lo + hi) >> 1; if (batch[mid] < val) lo = mid + 1; else hi = mid; }
    return lo;
}

__global__ void pool_kernel(const __bf16* __restrict__ h2b, const int* __restrict__ batch,
                            float* __restrict__ pooled) {
    int b = blockIdx.x, part = blockIdx.y;   // grid (B, 8)
    int tid = threadIdx.x;
    int start = lower_bound_batch(batch, b);
    int end   = lower_bound_batch(batch, b + 1);
    int len = end - start;
    int chunk = (len + 7) / 8;
    int s0 = start + part * chunk;
    int s1 = min(s0 + chunk, end);
    float acc[4] = {0.f, 0.f, 0.f, 0.f};
    for (int n = s0; n < s1; ++n) {
        bf16x4 v = ((const bf16x4*)(h2b + (size_t)n * HC))[tid];
        #pragma unroll
        for (int k = 0; k < 4; ++k) acc[k] += (float)v[k];
    }
    #pragma unroll
    for (int k = 0; k < 4; ++k)
        atomicAdd(&pooled[b * HC + tid * 4 + k], acc[k]);
}

// ---------------- projection (k-split) + layernorm ----------------

__global__ __launch_bounds__(512) void proj_partial_kernel(const float* __restrict__ pooled,
                                                           const int* __restrict__ batch,
                                                           const float* __restrict__ projW,
                                                           float* __restrict__ projOut) {
    int b = blockIdx.x, part = blockIdx.y;   // grid (16, 8)
    int d = threadIdx.x;                     // 512
    int start = lower_bound_batch(batch, b);
    int end   = lower_bound_batch(batch, b + 1);
    float inv = 1.0f / fmaxf((float)(end - start), 1.0f);
    float acc = 0.f;
    int k0 = part * 128;
    for (int k = k0; k < k0 + 128; ++k)
        acc += pooled[b * HC + k] * projW[(size_t)k * Dd + d];
    atomicAdd(&projOut[b * Dd + d], acc * inv);
}

__global__ __launch_bounds__(512) void ln_kernel(const float* __restrict__ projOut,
                                                 const float* __restrict__ projb,
                                                 const float* __restrict__ gamma,
                                                 const float* __restrict__ beta,
                                                 float* __restrict__ out) {
    int b = blockIdx.x;
    int d = threadIdx.x;
    __shared__ float red[512];
    float o = projOut[b * Dd + d] + projb[d];
    red[d] = o;
    __syncthreads();
    for (int off = 256; off > 0; off >>= 1) {
        if (d < off) red[d] += red[d + off];
        __syncthreads();
    }
    float mu = red[0] / (float)Dd;
    __syncthreads();
    float df = o - mu;
    red[d] = df * df;
    __syncthreads();
    for (int off = 256; off > 0; off >>= 1) {
        if (d < off) red[d] += red[d + off];
        __syncthreads();
    }
    float var = red[0] / (float)Dd;
    out[b * Dd + d] = df / sqrtf(var + LN_EPS) * gamma[d] + beta[d];
}

// ---------------- launch ----------------

extern "C" void kernel_launch(void* const* d_in, const int* in_sizes, int n_in,
                              void* d_out, int out_size, void* d_ws, size_t ws_size,
                              hipStream_t stream) {
    const float* x         = (const float*)d_in[0];
    const int*   ei        = (const int*)d_in[1];
    const int*   batch     = (const int*)d_in[2];
    const float* W0        = (const float*)d_in[3];
    const float* W_rest    = (const float*)d_in[4];
    const float* att_src   = (const float*)d_in[5];
    const float* att_dst   = (const float*)d_in[6];
    const float* conv_bias = (const float*)d_in[7];
    const float* proj_W    = (const float*)d_in[8];
    const float* proj_b    = (const float*)d_in[9];
    const float* ln_gamma  = (const float*)d_in[10];
    const float* ln_beta   = (const float*)d_in[11];
    float* out = (float*)d_out;

    char* ws = (char*)d_ws;
    size_t off = 0;
    auto alloc = [&](size_t bytes) {
        void* p = ws + off;
        off = (off + bytes + 255) & ~(size_t)255;
        return p;
    };
    __bf16* h1b     = (__bf16*)alloc((size_t)Nn * HC * 2);   // GEMM out (bf16)
    __bf16* h2b     = (__bf16*)alloc((size_t)Nn * HC * 2);   // layer out (bf16)
    __bf16* xb      = (__bf16*)alloc((size_t)Nn * Dd * 2);
    __bf16* W0T     = (__bf16*)alloc((size_t)HC * Dd * 2);
    __bf16* WrT     = (__bf16*)alloc((size_t)3 * HC * HC * 2);
    float*  asrc    = (float*)alloc((size_t)Nn * Hh * 4);    // contiguous with adst
    float*  adst    = (float*)alloc((size_t)Nn * Hh * 4);
    int*    deg     = (int*)alloc((size_t)Nn * 4);
    int*    tmp     = (int*)alloc((size_t)Nn * 4);
    int*    bsum    = (int*)alloc((size_t)256 * 4);
    int*    row_ptr = (int*)alloc((size_t)(Nn + 1) * 4);
    int*    cursor  = (int*)alloc((size_t)Nn * 4);
    int*    csr_src = (int*)alloc((size_t)ETOT * 4);
    float*  pooled  = (float*)alloc((size_t)Bb * HC * 4);
    float*  projOut = (float*)alloc((size_t)Bb * Dd * 4);
    (void)ws_size; (void)in_sizes; (void)n_in; (void)out_size;

    // ---- build CSR by destination ----
    hipMemsetAsync(deg, 0, (size_t)Nn * 4, stream);
    count_deg_kernel<<<(ETOT + 255) / 256, 256, 0, stream>>>(ei, deg);
    scan1_kernel<<<NBLK, 256, 0, stream>>>(deg, tmp, bsum);
    scan2_kernel<<<1, 256, 0, stream>>>(bsum);
    scan3_kernel<<<NBLK, 256, 0, stream>>>(tmp, bsum, deg, row_ptr, cursor);
    scatter_kernel<<<(ETOT + 255) / 256, 256, 0, stream>>>(ei, cursor, csr_src);

    // ---- bf16 casts / weight transposes ----
    cast_kernel<<<(Nn * Dd / 4 + 255) / 256, 256, 0, stream>>>(x, xb, Nn * Dd / 4);
    transpose_cast_kernel<<<dim3(HC / 32, Dd / 32), dim3(32, 8), 0, stream>>>(W0, W0T, Dd, HC);
    for (int l = 0; l < 3; ++l)
        transpose_cast_kernel<<<dim3(HC / 32, HC / 32), dim3(32, 8), 0, stream>>>(
            W_rest + (size_t)l * HC * HC, WrT + (size_t)l * HC * HC, HC, HC);

    // ---- GAT layers ----
    dim3 gemm_grid(HC / 128, (Nn + 127) / 128);   // (8, 157)
    for (int l = 0; l < Ll; ++l) {
        const __bf16* Afeat = (l == 0) ? xb : h2b;
        int K = (l == 0) ? Dd : HC;
        const __bf16* BT = (l == 0) ? W0T : (WrT + (size_t)(l - 1) * HC * HC);
        hipMemsetAsync(asrc, 0, (size_t)Nn * Hh * 4 * 2, stream);   // asrc+adst contiguous
        mfma_gemm_kernel<<<gemm_grid, 256, 0, stream>>>(
            Afeat, BT, h1b, att_src + l * HC, att_dst + l * HC, asrc, adst, Nn, K);
        agg_kernel<<<Nn, 256, 0, stream>>>(h1b, asrc, adst, row_ptr, csr_src,
                                           conv_bias + l * HC, h2b);
    }

    // ---- pool + proj + layernorm ----
    hipMemsetAsync(pooled, 0, (size_t)Bb * HC * 4, stream);
    hipMemsetAsync(projOut, 0, (size_t)Bb * Dd * 4, stream);
    pool_kernel<<<dim3(Bb, 8), 256, 0, stream>>>(h2b, batch, pooled);
    proj_partial_kernel<<<dim3(Bb, 8), 512, 0, stream>>>(pooled, batch, proj_W, projOut);
    ln_kernel<<<Bb, 512, 0, stream>>>(projOut, proj_b, ln_gamma, ln_beta, out);
}